// Round 1
// baseline (26187.204 us; speedup 1.0000x reference)
//
#include <hip/hip_runtime.h>
#include <hip/hip_bf16.h>
#include <math.h>

#define B_   32
#define SEQ_ 361
#define C_   768
#define H_   12
#define HD_  64
#define FFN_ 2048
#define L_   8
#define M_   (B_*SEQ_)        // 11552
#define MBLK ((M_ + 63) / 64) // 181

// ---------------- x_g = input_global @ Wg  (bias per (b, c)) ----------------
__global__ void bias_kernel(const float* __restrict__ inG, const float* __restrict__ Wg,
                            float* __restrict__ bias) {
  int idx = blockIdx.x * blockDim.x + threadIdx.x;
  if (idx >= B_ * C_) return;
  int b = idx / C_, c = idx - b * C_;
  float acc = 0.f;
  #pragma unroll
  for (int j = 0; j < 19; ++j) acc += inG[b * 19 + j] * Wg[j * C_ + c];
  bias[idx] = acc;
}

// ---------------- RoPE cos/sin tables: (SEQ, 64) each ----------------
__global__ void rope_table_kernel(float* __restrict__ cost, float* __restrict__ sint) {
  int idx = blockIdx.x * blockDim.x + threadIdx.x;  // SEQ_*32
  if (idx >= SEQ_ * 32) return;
  int s = idx / 32, j = idx - s * 32;
  float row = (float)(s / 19), col = (float)(s % 19);
  int q = (j < 16) ? j : (j - 16);
  float invf = powf(10000.f, -(float)q / 16.f);
  float ang = ((j < 16) ? row : col) * invf;
  float cv = cosf(ang), sv = sinf(ang);
  cost[s * 64 + j] = cv; cost[s * 64 + j + 32] = cv;
  sint[s * 64 + j] = sv; sint[s * 64 + j + 32] = sv;
}

// ---------------- conv3x3 SAME (22->768) + bias, writes x as (M, C) ----------------
__global__ __launch_bounds__(256) void conv_kernel(const float* __restrict__ inS,
    const float* __restrict__ convW, const float* __restrict__ bias,
    float* __restrict__ X) {
  __shared__ float in_l[22][441];   // 21x21 zero-padded per channel
  __shared__ float w_l[24][198];
  int b = blockIdx.x;
  int cb = blockIdx.y * 24;
  int tid = threadIdx.x;
  for (int i = tid; i < 22 * 441; i += 256) (&in_l[0][0])[i] = 0.f;
  __syncthreads();
  for (int i = tid; i < 22 * 361; i += 256) {
    int ci = i / 361, s = i - ci * 361, r = s / 19, c = s - r * 19;
    in_l[ci][(r + 1) * 21 + (c + 1)] = inS[(size_t)(b * 22 + ci) * 361 + s];
  }
  for (int i = tid; i < 24 * 198; i += 256)
    (&w_l[0][0])[i] = convW[(size_t)cb * 198 + i];
  __syncthreads();
  for (int o = tid; o < 24 * 361; o += 256) {
    int col = o / 361, s = o - col * 361, r = s / 19, c = s - r * 19;
    float acc = bias[b * C_ + cb + col];
    const float* wr = &w_l[col][0];
    #pragma unroll
    for (int ci = 0; ci < 22; ++ci) {
      const float* ib = &in_l[ci][r * 21 + c];
      const float* wp = wr + ci * 9;
      acc += wp[0]*ib[0]  + wp[1]*ib[1]  + wp[2]*ib[2]
           + wp[3]*ib[21] + wp[4]*ib[22] + wp[5]*ib[23]
           + wp[6]*ib[42] + wp[7]*ib[43] + wp[8]*ib[44];
    }
    X[(size_t)(b * SEQ_ + s) * C_ + cb + col] = acc;
  }
}

// ---------------- RMSNorm over last dim (C=768), one block per row ----------------
__global__ __launch_bounds__(256) void rmsnorm_kernel(const float* __restrict__ X,
    const float* __restrict__ gamma, float* __restrict__ Out) {
  int row = blockIdx.x;
  const float* xp = X + (size_t)row * C_;
  int t = threadIdx.x;
  float v0 = xp[t], v1 = xp[t + 256], v2 = xp[t + 512];
  float ss = v0 * v0 + v1 * v1 + v2 * v2;
  #pragma unroll
  for (int off = 32; off > 0; off >>= 1) ss += __shfl_down(ss, off);
  __shared__ float ws4[4];
  if ((t & 63) == 0) ws4[t >> 6] = ss;
  __syncthreads();
  float tot = ws4[0] + ws4[1] + ws4[2] + ws4[3];
  float r = 1.0f / sqrtf(tot * (1.f / 768.f) + 1e-6f);
  float* op = Out + (size_t)row * C_;
  op[t]       = v0 * r * gamma[t];
  op[t + 256] = v1 * r * gamma[t + 256];
  op[t + 512] = v2 * r * gamma[t + 512];
}

// ---------------- generic fp32 GEMM: C = A(MxK) @ B(KxN) [+ Res] ----------------
__global__ __launch_bounds__(256) void gemm_kernel(const float* __restrict__ A,
    const float* __restrict__ Bw, float* __restrict__ Cout,
    const float* __restrict__ Res, int M, int N, int K) {
  __shared__ float As[16][65];
  __shared__ float Bs[16][64];
  int tid = threadIdx.x;
  int bm = blockIdx.y * 64;
  int bn = blockIdx.x * 64;
  int tx  = (tid & 15) * 4;
  int tyb = (tid >> 4) * 4;
  int la_r = tid >> 2, la_k = (tid & 3) * 4;
  int lb_k = tid >> 4, lb_n = (tid & 15) * 4;
  float acc[4][4] = {{0.f}};
  bool a_ok = (bm + la_r) < M;
  const float* Ap  = A  + (size_t)(bm + la_r) * K + la_k;
  const float* Bp  = Bw + (size_t)lb_k * N + bn + lb_n;
  for (int kt = 0; kt < K; kt += 16) {
    float4 av = a_ok ? *reinterpret_cast<const float4*>(Ap + kt)
                     : make_float4(0.f, 0.f, 0.f, 0.f);
    As[la_k + 0][la_r] = av.x;
    As[la_k + 1][la_r] = av.y;
    As[la_k + 2][la_r] = av.z;
    As[la_k + 3][la_r] = av.w;
    *reinterpret_cast<float4*>(&Bs[lb_k][lb_n]) =
        *reinterpret_cast<const float4*>(Bp + (size_t)kt * N);
    __syncthreads();
    #pragma unroll
    for (int k = 0; k < 16; ++k) {
      float a0 = As[k][tyb + 0], a1 = As[k][tyb + 1];
      float a2 = As[k][tyb + 2], a3 = As[k][tyb + 3];
      float4 b4 = *reinterpret_cast<const float4*>(&Bs[k][tx]);
      acc[0][0] = fmaf(a0, b4.x, acc[0][0]); acc[0][1] = fmaf(a0, b4.y, acc[0][1]);
      acc[0][2] = fmaf(a0, b4.z, acc[0][2]); acc[0][3] = fmaf(a0, b4.w, acc[0][3]);
      acc[1][0] = fmaf(a1, b4.x, acc[1][0]); acc[1][1] = fmaf(a1, b4.y, acc[1][1]);
      acc[1][2] = fmaf(a1, b4.z, acc[1][2]); acc[1][3] = fmaf(a1, b4.w, acc[1][3]);
      acc[2][0] = fmaf(a2, b4.x, acc[2][0]); acc[2][1] = fmaf(a2, b4.y, acc[2][1]);
      acc[2][2] = fmaf(a2, b4.z, acc[2][2]); acc[2][3] = fmaf(a2, b4.w, acc[2][3]);
      acc[3][0] = fmaf(a3, b4.x, acc[3][0]); acc[3][1] = fmaf(a3, b4.y, acc[3][1]);
      acc[3][2] = fmaf(a3, b4.z, acc[3][2]); acc[3][3] = fmaf(a3, b4.w, acc[3][3]);
    }
    __syncthreads();
  }
  #pragma unroll
  for (int i = 0; i < 4; ++i) {
    int r = bm + tyb + i;
    if (r < M) {
      float4 o;
      o.x = acc[i][0]; o.y = acc[i][1]; o.z = acc[i][2]; o.w = acc[i][3];
      if (Res) {
        float4 rv = *reinterpret_cast<const float4*>(&Res[(size_t)r * N + bn + tx]);
        o.x += rv.x; o.y += rv.y; o.z += rv.z; o.w += rv.w;
      }
      *reinterpret_cast<float4*>(&Cout[(size_t)r * N + bn + tx]) = o;
    }
  }
}

// ---------------- fused fc1 + silu-gate: G = silu(h@W[:, :2048]) * (h@W[:, 2048:]) ----------------
__global__ __launch_bounds__(256) void gemm_gate_kernel(const float* __restrict__ A,
    const float* __restrict__ Bw, float* __restrict__ G, int M) {
  const int K = C_, N = 2 * FFN_;
  __shared__ float As[16][65];
  __shared__ float Bs0[16][64];
  __shared__ float Bs1[16][64];
  int tid = threadIdx.x;
  int bm = blockIdx.y * 64;
  int bn = blockIdx.x * 64;   // column tile within [0, 2048)
  int tx  = (tid & 15) * 4;
  int tyb = (tid >> 4) * 4;
  int la_r = tid >> 2, la_k = (tid & 3) * 4;
  int lb_k = tid >> 4, lb_n = (tid & 15) * 4;
  float accA[4][4] = {{0.f}}, accB[4][4] = {{0.f}};
  bool a_ok = (bm + la_r) < M;
  const float* Ap  = A + (size_t)(bm + la_r) * K + la_k;
  const float* Bp0 = Bw + (size_t)lb_k * N + bn + lb_n;
  const float* Bp1 = Bp0 + FFN_;
  for (int kt = 0; kt < K; kt += 16) {
    float4 av = a_ok ? *reinterpret_cast<const float4*>(Ap + kt)
                     : make_float4(0.f, 0.f, 0.f, 0.f);
    As[la_k + 0][la_r] = av.x;
    As[la_k + 1][la_r] = av.y;
    As[la_k + 2][la_r] = av.z;
    As[la_k + 3][la_r] = av.w;
    *reinterpret_cast<float4*>(&Bs0[lb_k][lb_n]) =
        *reinterpret_cast<const float4*>(Bp0 + (size_t)kt * N);
    *reinterpret_cast<float4*>(&Bs1[lb_k][lb_n]) =
        *reinterpret_cast<const float4*>(Bp1 + (size_t)kt * N);
    __syncthreads();
    #pragma unroll
    for (int k = 0; k < 16; ++k) {
      float a0 = As[k][tyb + 0], a1 = As[k][tyb + 1];
      float a2 = As[k][tyb + 2], a3 = As[k][tyb + 3];
      float4 b0 = *reinterpret_cast<const float4*>(&Bs0[k][tx]);
      float4 b1 = *reinterpret_cast<const float4*>(&Bs1[k][tx]);
      accA[0][0] = fmaf(a0, b0.x, accA[0][0]); accA[0][1] = fmaf(a0, b0.y, accA[0][1]);
      accA[0][2] = fmaf(a0, b0.z, accA[0][2]); accA[0][3] = fmaf(a0, b0.w, accA[0][3]);
      accA[1][0] = fmaf(a1, b0.x, accA[1][0]); accA[1][1] = fmaf(a1, b0.y, accA[1][1]);
      accA[1][2] = fmaf(a1, b0.z, accA[1][2]); accA[1][3] = fmaf(a1, b0.w, accA[1][3]);
      accA[2][0] = fmaf(a2, b0.x, accA[2][0]); accA[2][1] = fmaf(a2, b0.y, accA[2][1]);
      accA[2][2] = fmaf(a2, b0.z, accA[2][2]); accA[2][3] = fmaf(a2, b0.w, accA[2][3]);
      accA[3][0] = fmaf(a3, b0.x, accA[3][0]); accA[3][1] = fmaf(a3, b0.y, accA[3][1]);
      accA[3][2] = fmaf(a3, b0.z, accA[3][2]); accA[3][3] = fmaf(a3, b0.w, accA[3][3]);
      accB[0][0] = fmaf(a0, b1.x, accB[0][0]); accB[0][1] = fmaf(a0, b1.y, accB[0][1]);
      accB[0][2] = fmaf(a0, b1.z, accB[0][2]); accB[0][3] = fmaf(a0, b1.w, accB[0][3]);
      accB[1][0] = fmaf(a1, b1.x, accB[1][0]); accB[1][1] = fmaf(a1, b1.y, accB[1][1]);
      accB[1][2] = fmaf(a1, b1.z, accB[1][2]); accB[1][3] = fmaf(a1, b1.w, accB[1][3]);
      accB[2][0] = fmaf(a2, b1.x, accB[2][0]); accB[2][1] = fmaf(a2, b1.y, accB[2][1]);
      accB[2][2] = fmaf(a2, b1.z, accB[2][2]); accB[2][3] = fmaf(a2, b1.w, accB[2][3]);
      accB[3][0] = fmaf(a3, b1.x, accB[3][0]); accB[3][1] = fmaf(a3, b1.y, accB[3][1]);
      accB[3][2] = fmaf(a3, b1.z, accB[3][2]); accB[3][3] = fmaf(a3, b1.w, accB[3][3]);
    }
    __syncthreads();
  }
  #pragma unroll
  for (int i = 0; i < 4; ++i) {
    int r = bm + tyb + i;
    if (r < M) {
      float4 g4;
      float a;
      a = accA[i][0]; g4.x = a / (1.f + expf(-a)) * accB[i][0];
      a = accA[i][1]; g4.y = a / (1.f + expf(-a)) * accB[i][1];
      a = accA[i][2]; g4.z = a / (1.f + expf(-a)) * accB[i][2];
      a = accA[i][3]; g4.w = a / (1.f + expf(-a)) * accB[i][3];
      *reinterpret_cast<float4*>(&G[(size_t)r * FFN_ + bn + tx]) = g4;
    }
  }
}

// ---------------- RoPE in-place on q,k slices of qkv ----------------
__global__ void rope_apply_kernel(float* __restrict__ qkv,
    const float* __restrict__ cost, const float* __restrict__ sint) {
  int idx = blockIdx.x * blockDim.x + threadIdx.x;
  const int total = M_ * 2 * H_ * 32;   // (b,s) x {q,k} x head x half-dim
  if (idx >= total) return;
  int d = idx & 31;
  int rest = idx >> 5;
  int h = rest % H_; rest /= H_;
  int which = rest & 1; rest >>= 1;  // 0=q, 1=k
  int s = rest % SEQ_;
  int b = rest / SEQ_;
  size_t base = (size_t)(b * SEQ_ + s) * (3 * C_) + which * C_ + h * 64;
  float a  = qkv[base + d];
  float bb = qkv[base + d + 32];
  float cv = cost[s * 64 + d], sv = sint[s * 64 + d];
  qkv[base + d]      = a * cv - bb * sv;
  qkv[base + d + 32] = bb * cv + a * sv;
}

// ---------------- fused flash attention: 1 wave per (64 q-rows, h, b) ----------------
__global__ __launch_bounds__(64) void attn_kernel(const float* __restrict__ qkv,
                                                  float* __restrict__ Out) {
  __shared__ float Kl[64][64];
  __shared__ float Vl[64][64];
  __shared__ float Sl[64][65];
  int lane = threadIdx.x;
  int q0 = blockIdx.x * 64;
  int h = blockIdx.y, b = blockIdx.z;
  int row = q0 + lane;
  bool valid = row < SEQ_;
  int rc = valid ? row : (SEQ_ - 1);
  const float* qp = qkv + (size_t)(b * SEQ_ + rc) * (3 * C_) + h * 64;
  float4 q4[16];
  #pragma unroll
  for (int i = 0; i < 16; ++i) q4[i] = reinterpret_cast<const float4*>(qp)[i];
  float4 o4[16];
  #pragma unroll
  for (int i = 0; i < 16; ++i) o4[i] = make_float4(0.f, 0.f, 0.f, 0.f);
  float mrun = -INFINITY, lrun = 0.f;

  for (int kt = 0; kt < SEQ_; kt += 64) {
    int kn = min(64, SEQ_ - kt);
    // cooperative coalesced K/V tile load: 4 rows x 64 cols per iteration
    #pragma unroll 4
    for (int it = 0; it < 16; ++it) {
      int rr = it * 4 + (lane >> 4);
      int cc = (lane & 15) * 4;
      int krow = kt + rr;
      int kc = (krow < SEQ_) ? krow : (SEQ_ - 1);
      const float* kb = qkv + (size_t)(b * SEQ_ + kc) * (3 * C_) + C_     + h * 64 + cc;
      const float* vb = qkv + (size_t)(b * SEQ_ + kc) * (3 * C_) + 2 * C_ + h * 64 + cc;
      float4 kv = *reinterpret_cast<const float4*>(kb);
      float4 vv = *reinterpret_cast<const float4*>(vb);
      if (krow >= SEQ_) { kv = make_float4(0,0,0,0); vv = make_float4(0,0,0,0); }
      *reinterpret_cast<float4*>(&Kl[rr][cc]) = kv;
      *reinterpret_cast<float4*>(&Vl[rr][cc]) = vv;
    }
    __syncthreads();
    float mnew = mrun;
    for (int j = 0; j < 64; ++j) {
      float acc = 0.f;
      #pragma unroll
      for (int dq = 0; dq < 16; ++dq) {
        float4 kk = *reinterpret_cast<const float4*>(&Kl[j][dq * 4]);
        acc += q4[dq].x * kk.x + q4[dq].y * kk.y + q4[dq].z * kk.z + q4[dq].w * kk.w;
      }
      acc *= 0.125f;                       // 1/sqrt(64)
      if (j >= kn) acc = -INFINITY;
      Sl[lane][j] = acc;
      mnew = fmaxf(mnew, acc);
    }
    float rescale = expf(mrun - mnew);     // first tile: exp(-inf)=0
    float psum = 0.f;
    for (int j = 0; j < 64; ++j) {
      float p = expf(Sl[lane][j] - mnew);  // -inf cols -> 0
      Sl[lane][j] = p;
      psum += p;
    }
    lrun = lrun * rescale + psum;
    #pragma unroll
    for (int i = 0; i < 16; ++i) {
      o4[i].x *= rescale; o4[i].y *= rescale; o4[i].z *= rescale; o4[i].w *= rescale;
    }
    for (int j = 0; j < 64; ++j) {
      float p = Sl[lane][j];
      #pragma unroll
      for (int dq = 0; dq < 16; ++dq) {
        float4 vv = *reinterpret_cast<const float4*>(&Vl[j][dq * 4]);
        o4[dq].x = fmaf(p, vv.x, o4[dq].x);
        o4[dq].y = fmaf(p, vv.y, o4[dq].y);
        o4[dq].z = fmaf(p, vv.z, o4[dq].z);
        o4[dq].w = fmaf(p, vv.w, o4[dq].w);
      }
    }
    mrun = mnew;
    __syncthreads();
  }
  if (valid) {
    float inv = 1.f / lrun;
    float* op = Out + (size_t)(b * SEQ_ + row) * C_ + h * 64;
    #pragma unroll
    for (int i = 0; i < 16; ++i) {
      float4 w = make_float4(o4[i].x * inv, o4[i].y * inv, o4[i].z * inv, o4[i].w * inv);
      reinterpret_cast<float4*>(op)[i] = w;
    }
  }
}

extern "C" void kernel_launch(void* const* d_in, const int* in_sizes, int n_in,
                              void* d_out, int out_size, void* d_ws, size_t ws_size,
                              hipStream_t stream) {
  (void)in_sizes; (void)n_in; (void)out_size; (void)ws_size;
  const float* inS   = (const float*)d_in[0];
  const float* inG   = (const float*)d_in[1];
  const float* convW = (const float*)d_in[2];
  const float* Wg    = (const float*)d_in[3];
  const float* qg    = (const float*)d_in[4];
  const float* Wqkv  = (const float*)d_in[5];
  const float* Wproj = (const float*)d_in[6];
  const float* mg    = (const float*)d_in[7];
  const float* Wfc1  = (const float*)d_in[8];
  const float* Wfc2  = (const float*)d_in[9];
  const float* fg    = (const float*)d_in[10];
  float* out = (float*)d_out;

  const size_t MC = (size_t)M_ * C_;
  float* ws   = (float*)d_ws;
  float* x    = ws;                               // M x C
  float* hbuf = x + MC;                           // M x C (rmsnorm out; attn out)
  float* qkv  = hbuf + MC;                        // M x 3C  (reused as gate out M x FFN)
  float* bias = qkv + (size_t)M_ * 3 * C_;        // B x C
  float* cost = bias + (size_t)B_ * C_;           // SEQ x 64
  float* sint = cost + (size_t)SEQ_ * 64;         // SEQ x 64
  float* g    = qkv;                              // reuse (qkv dead after attention)

  bias_kernel<<<dim3((B_ * C_ + 255) / 256), 256, 0, stream>>>(inG, Wg, bias);
  rope_table_kernel<<<dim3((SEQ_ * 32 + 255) / 256), 256, 0, stream>>>(cost, sint);
  conv_kernel<<<dim3(B_, 32), 256, 0, stream>>>(inS, convW, bias, x);

  for (int i = 0; i < L_; ++i) {
    rmsnorm_kernel<<<M_, 256, 0, stream>>>(x, qg + (size_t)i * C_, hbuf);
    gemm_kernel<<<dim3(3 * C_ / 64, MBLK), 256, 0, stream>>>(
        hbuf, Wqkv + (size_t)i * C_ * 3 * C_, qkv, nullptr, M_, 3 * C_, C_);
    rope_apply_kernel<<<dim3((M_ * 2 * H_ * 32 + 255) / 256), 256, 0, stream>>>(qkv, cost, sint);
    attn_kernel<<<dim3(6, H_, B_), 64, 0, stream>>>(qkv, hbuf);
    gemm_kernel<<<dim3(C_ / 64, MBLK), 256, 0, stream>>>(
        hbuf, Wproj + (size_t)i * C_ * C_, x, x, M_, C_, C_);
    rmsnorm_kernel<<<M_, 256, 0, stream>>>(x, mg + (size_t)i * C_, hbuf);
    gemm_gate_kernel<<<dim3(FFN_ / 64, MBLK), 256, 0, stream>>>(
        hbuf, Wfc1 + (size_t)i * C_ * 2 * FFN_, g, M_);
    gemm_kernel<<<dim3(C_ / 64, MBLK), 256, 0, stream>>>(
        g, Wfc2 + (size_t)i * FFN_ * C_, x, x, M_, C_, FFN_);
  }
  rmsnorm_kernel<<<M_, 256, 0, stream>>>(x, fg, out);
}

// Round 3
// 3665.885 us; speedup vs baseline: 7.1435x; 7.1435x over previous
//
#include <hip/hip_runtime.h>
#include <hip/hip_bf16.h>
#include <math.h>

#define B_    32
#define SEQ_  361
#define C_    768
#define H_    12
#define HD_   64
#define FFN_  2048
#define L_    8
#define M_    (B_*SEQ_)          // 11552
#define MPAD_ 11648              // 91 * 128
#define MBLK_ (MPAD_/128)        // 91

typedef _Float16 f16;
typedef f16  f16x8 __attribute__((ext_vector_type(8)));
typedef float f32x4 __attribute__((ext_vector_type(4)));

// ---------------- x_g = input_global @ Wg  (bias per (b, c)) ----------------
__global__ void bias_kernel(const float* __restrict__ inG, const float* __restrict__ Wg,
                            float* __restrict__ bias) {
  int idx = blockIdx.x * blockDim.x + threadIdx.x;
  if (idx >= B_ * C_) return;
  int b = idx / C_, c = idx - b * C_;
  float acc = 0.f;
  #pragma unroll
  for (int j = 0; j < 19; ++j) acc += inG[b * 19 + j] * Wg[j * C_ + c];
  bias[idx] = acc;
}

// ---------------- RoPE cos/sin tables: (SEQ, 64) each ----------------
__global__ void rope_table_kernel(float* __restrict__ cost, float* __restrict__ sint) {
  int idx = blockIdx.x * blockDim.x + threadIdx.x;
  if (idx >= SEQ_ * 32) return;
  int s = idx / 32, j = idx - s * 32;
  float row = (float)(s / 19), col = (float)(s % 19);
  int q = (j < 16) ? j : (j - 16);
  float invf = powf(10000.f, -(float)q / 16.f);
  float ang = ((j < 16) ? row : col) * invf;
  float cv = cosf(ang), sv = sinf(ang);
  cost[s * 64 + j] = cv; cost[s * 64 + j + 32] = cv;
  sint[s * 64 + j] = sv; sint[s * 64 + j + 32] = sv;
}

// ---------------- conv3x3 SAME (22->768) + bias, writes x (MPAD, C) fp32 ----------------
__global__ __launch_bounds__(256) void conv_kernel(const float* __restrict__ inS,
    const float* __restrict__ convW, const float* __restrict__ bias,
    float* __restrict__ X) {
  __shared__ float in_l[22][441];
  __shared__ float w_l[24][198];
  int b = blockIdx.x;
  int cb = blockIdx.y * 24;
  int tid = threadIdx.x;
  for (int i = tid; i < 22 * 441; i += 256) (&in_l[0][0])[i] = 0.f;
  __syncthreads();
  for (int i = tid; i < 22 * 361; i += 256) {
    int ci = i / 361, s = i - ci * 361, r = s / 19, c = s - r * 19;
    in_l[ci][(r + 1) * 21 + (c + 1)] = inS[(size_t)(b * 22 + ci) * 361 + s];
  }
  for (int i = tid; i < 24 * 198; i += 256)
    (&w_l[0][0])[i] = convW[(size_t)cb * 198 + i];
  __syncthreads();
  for (int o = tid; o < 24 * 361; o += 256) {
    int col = o / 361, s = o - col * 361, r = s / 19, c = s - r * 19;
    float acc = bias[b * C_ + cb + col];
    const float* wr = &w_l[col][0];
    #pragma unroll
    for (int ci = 0; ci < 22; ++ci) {
      const float* ib = &in_l[ci][r * 21 + c];
      const float* wp = wr + ci * 9;
      acc += wp[0]*ib[0]  + wp[1]*ib[1]  + wp[2]*ib[2]
           + wp[3]*ib[21] + wp[4]*ib[22] + wp[5]*ib[23]
           + wp[6]*ib[42] + wp[7]*ib[43] + wp[8]*ib[44];
    }
    X[(size_t)(b * SEQ_ + s) * C_ + cb + col] = acc;
  }
}

// ---------------- weight convert + transpose: W[K][N] f32 -> WT[N][K] f16 ----------------
__global__ __launch_bounds__(256) void wcvt_kernel(const float* __restrict__ W,
    f16* __restrict__ WT, int K, int N) {
  __shared__ float t[32][33];
  int n0 = blockIdx.x * 32, k0 = blockIdx.y * 32;
  size_t base = (size_t)blockIdx.z * K * N;
  int c = threadIdx.x & 31, r = threadIdx.x >> 5;
  #pragma unroll
  for (int rr = 0; rr < 32; rr += 8)
    t[r + rr][c] = W[base + (size_t)(k0 + r + rr) * N + n0 + c];
  __syncthreads();
  #pragma unroll
  for (int rr = 0; rr < 32; rr += 8)
    WT[base + (size_t)(n0 + r + rr) * K + k0 + c] = (f16)t[c][r + rr];
}

// ---------------- RMSNorm (C=768), one block per row; f16 or f32 out ----------------
template<bool F16OUT>
__global__ __launch_bounds__(256) void rmsnorm_kernel(const float* __restrict__ X,
    const float* __restrict__ gamma, void* __restrict__ Out) {
  int row = blockIdx.x;
  const float* xp = X + (size_t)row * C_;
  int t = threadIdx.x;
  float v0 = xp[t], v1 = xp[t + 256], v2 = xp[t + 512];
  float ss = v0 * v0 + v1 * v1 + v2 * v2;
  #pragma unroll
  for (int off = 32; off > 0; off >>= 1) ss += __shfl_down(ss, off);
  __shared__ float ws4[4];
  if ((t & 63) == 0) ws4[t >> 6] = ss;
  __syncthreads();
  float tot = ws4[0] + ws4[1] + ws4[2] + ws4[3];
  float r = 1.0f / sqrtf(tot * (1.f / 768.f) + 1e-6f);
  if (F16OUT) {
    f16* op = (f16*)Out + (size_t)row * C_;
    op[t]       = (f16)(v0 * r * gamma[t]);
    op[t + 256] = (f16)(v1 * r * gamma[t + 256]);
    op[t + 512] = (f16)(v2 * r * gamma[t + 512]);
  } else {
    float* op = (float*)Out + (size_t)row * C_;
    op[t]       = v0 * r * gamma[t];
    op[t + 256] = v1 * r * gamma[t + 256];
    op[t + 512] = v2 * r * gamma[t + 512];
  }
}

// ---------------- f16 MFMA GEMM: C = A(MPADxK,f16) @ BT(NxK,f16)^T ----------------
// MODE 0: write f16 to Cout (stride N). MODE 1: Cout fp32 += acc (stride N).
// Tiles: BM=128 BN=128 BK=32; 4 waves (2x2), 64x64 per wave, 4x4 16x16x32 frags.
// LDS tiles [128 rows][32 f16], chunk-XOR swizzle: phys chunk = chunk ^ ((row>>1)&3).
template<int MODE>
__global__ __launch_bounds__(256, 2) void hgemm(const f16* __restrict__ A,
    const f16* __restrict__ BT, void* __restrict__ Cout, int N, int K) {
  __shared__ f16 As[128 * 32];
  __shared__ f16 Bs[128 * 32];
  int tid = threadIdx.x;
  int w = tid >> 6, lane = tid & 63, lo = lane & 15, hi = lane >> 4;
  int bm = blockIdx.y * 128, bn = blockIdx.x * 128;
  int wr = (w >> 1) * 64, wc = (w & 1) * 64;
  f32x4 acc[4][4] = {};
  f16x8 ra[2], rb[2];
  const f16* Abase = A  + (size_t)bm * K;
  const f16* Bbase = BT + (size_t)bn * K;

  auto loadT = [&](int kt) {
    #pragma unroll
    for (int c = 0; c < 2; ++c) {
      int id = c * 256 + tid;
      ra[c] = *(const f16x8*)(Abase + (size_t)(id >> 2) * K + kt + (id & 3) * 8);
      rb[c] = *(const f16x8*)(Bbase + (size_t)(id >> 2) * K + kt + (id & 3) * 8);
    }
  };
  auto writeT = [&]() {
    #pragma unroll
    for (int c = 0; c < 2; ++c) {
      int id = c * 256 + tid;
      int row = id >> 2, ch = id & 3;
      int off = row * 32 + ((ch ^ ((row >> 1) & 3)) << 3);
      *(f16x8*)(As + off) = ra[c];
      *(f16x8*)(Bs + off) = rb[c];
    }
  };

  loadT(0);
  for (int kt = 0; kt < K; kt += 32) {
    writeT();
    __syncthreads();
    if (kt + 32 < K) loadT(kt + 32);
    f16x8 af[4], bf[4];
    #pragma unroll
    for (int m = 0; m < 4; ++m) {
      int row = wr + m * 16 + lo;
      af[m] = *(const f16x8*)(As + row * 32 + ((hi ^ ((row >> 1) & 3)) << 3));
    }
    #pragma unroll
    for (int n = 0; n < 4; ++n) {
      int row = wc + n * 16 + lo;
      bf[n] = *(const f16x8*)(Bs + row * 32 + ((hi ^ ((row >> 1) & 3)) << 3));
    }
    #pragma unroll
    for (int m = 0; m < 4; ++m)
      #pragma unroll
      for (int n = 0; n < 4; ++n)
        acc[m][n] = __builtin_amdgcn_mfma_f32_16x16x32_f16(af[m], bf[n], acc[m][n], 0, 0, 0);
    __syncthreads();
  }

  #pragma unroll
  for (int m = 0; m < 4; ++m) {
    #pragma unroll
    for (int n = 0; n < 4; ++n) {
      #pragma unroll
      for (int r = 0; r < 4; ++r) {
        size_t off = (size_t)(bm + wr + m * 16 + hi * 4 + r) * N + bn + wc + n * 16 + lo;
        if (MODE == 0) {
          ((f16*)Cout)[off] = (f16)acc[m][n][r];
        } else {
          float* O = (float*)Cout;
          O[off] = O[off] + acc[m][n][r];
        }
      }
    }
  }
}

// ---------------- fused fc1 dual-tile + silu gate: G = silu(h@W0) * (h@W1), f16 out ----------------
__global__ __launch_bounds__(256, 2) void hgemm_gate(const f16* __restrict__ A,
    const f16* __restrict__ BT, f16* __restrict__ G) {
  const int K = C_;
  __shared__ f16 As[128 * 32];
  __shared__ f16 Bs0[64 * 32];
  __shared__ f16 Bs1[64 * 32];
  int tid = threadIdx.x;
  int w = tid >> 6, lane = tid & 63, lo = lane & 15, hi = lane >> 4;
  int bm = blockIdx.y * 128, bn = blockIdx.x * 64;
  int wr = (w >> 1) * 64, wc = (w & 1) * 32;
  f32x4 accA[4][2] = {}, accB[4][2] = {};
  f16x8 ra[2], rb0, rb1;
  const f16* Abase  = A + (size_t)bm * K;
  const f16* B0base = BT + (size_t)bn * K;
  const f16* B1base = BT + (size_t)(2048 + bn) * K;

  auto loadT = [&](int kt) {
    #pragma unroll
    for (int c = 0; c < 2; ++c) {
      int id = c * 256 + tid;
      ra[c] = *(const f16x8*)(Abase + (size_t)(id >> 2) * K + kt + (id & 3) * 8);
    }
    rb0 = *(const f16x8*)(B0base + (size_t)(tid >> 2) * K + kt + (tid & 3) * 8);
    rb1 = *(const f16x8*)(B1base + (size_t)(tid >> 2) * K + kt + (tid & 3) * 8);
  };
  auto writeT = [&]() {
    #pragma unroll
    for (int c = 0; c < 2; ++c) {
      int id = c * 256 + tid;
      int row = id >> 2, ch = id & 3;
      *(f16x8*)(As + row * 32 + ((ch ^ ((row >> 1) & 3)) << 3)) = ra[c];
    }
    int row = tid >> 2, ch = tid & 3;
    int off = row * 32 + ((ch ^ ((row >> 1) & 3)) << 3);
    *(f16x8*)(Bs0 + off) = rb0;
    *(f16x8*)(Bs1 + off) = rb1;
  };

  loadT(0);
  for (int kt = 0; kt < K; kt += 32) {
    writeT();
    __syncthreads();
    if (kt + 32 < K) loadT(kt + 32);
    f16x8 af[4], b0f[2], b1f[2];
    #pragma unroll
    for (int m = 0; m < 4; ++m) {
      int row = wr + m * 16 + lo;
      af[m] = *(const f16x8*)(As + row * 32 + ((hi ^ ((row >> 1) & 3)) << 3));
    }
    #pragma unroll
    for (int n = 0; n < 2; ++n) {
      int row = wc + n * 16 + lo;
      int off = row * 32 + ((hi ^ ((row >> 1) & 3)) << 3);
      b0f[n] = *(const f16x8*)(Bs0 + off);
      b1f[n] = *(const f16x8*)(Bs1 + off);
    }
    #pragma unroll
    for (int m = 0; m < 4; ++m)
      #pragma unroll
      for (int n = 0; n < 2; ++n) {
        accA[m][n] = __builtin_amdgcn_mfma_f32_16x16x32_f16(af[m], b0f[n], accA[m][n], 0, 0, 0);
        accB[m][n] = __builtin_amdgcn_mfma_f32_16x16x32_f16(af[m], b1f[n], accB[m][n], 0, 0, 0);
      }
    __syncthreads();
  }

  #pragma unroll
  for (int m = 0; m < 4; ++m)
    #pragma unroll
    for (int n = 0; n < 2; ++n)
      #pragma unroll
      for (int r = 0; r < 4; ++r) {
        float a = accA[m][n][r], bb = accB[m][n][r];
        float g = a / (1.f + expf(-a)) * bb;
        G[(size_t)(bm + wr + m * 16 + hi * 4 + r) * 2048 + bn + wc + n * 16 + lo] = (f16)g;
      }
}

// ---------------- RoPE in-place on f16 q,k slices of qkv ----------------
__global__ void rope_apply_kernel(f16* __restrict__ qkv,
    const float* __restrict__ cost, const float* __restrict__ sint) {
  int idx = blockIdx.x * blockDim.x + threadIdx.x;
  const int total = M_ * 2 * H_ * 32;
  if (idx >= total) return;
  int d = idx & 31;
  int rest = idx >> 5;
  int h = rest % H_; rest /= H_;
  int which = rest & 1; rest >>= 1;
  int s = rest % SEQ_;
  int b = rest / SEQ_;
  size_t base = (size_t)(b * SEQ_ + s) * (3 * C_) + which * C_ + h * 64;
  float a  = (float)qkv[base + d];
  float bb = (float)qkv[base + d + 32];
  float cv = cost[s * 64 + d], sv = sint[s * 64 + d];
  qkv[base + d]      = (f16)(a * cv - bb * sv);
  qkv[base + d + 32] = (f16)(bb * cv + a * sv);
}

// ---------------- MFMA flash attention: block = (64 q-rows, h, b), 4 waves ----------------
__global__ __launch_bounds__(256, 2) void attn_kernel(const f16* __restrict__ qkv,
                                                      f16* __restrict__ Out) {
  __shared__ f16 Kl[64 * 64];        // swizzled: chunk ^= (row&7)
  __shared__ f16 Vt[64 * 72];        // [d][key], pad 8
  __shared__ f16 Pl[4][16 * 72];     // per-wave P [q][key], pad 8
  int tid = threadIdx.x;
  int w = tid >> 6, lane = tid & 63, lo = lane & 15, hi = lane >> 4;
  int qt = blockIdx.x, h = blockIdx.y, b = blockIdx.z;
  int q0 = qt * 64 + w * 16;
  const int RS = 3 * C_;

  f16x8 qf[2];
  {
    int qrow = q0 + lo; if (qrow > 360) qrow = 360;
    const f16* qp = qkv + (size_t)(b * SEQ_ + qrow) * RS + h * 64 + hi * 8;
    qf[0] = *(const f16x8*)(qp);
    qf[1] = *(const f16x8*)(qp + 32);
  }
  f32x4 o[4] = {};
  float mrun[4], lrun[4];
  #pragma unroll
  for (int r = 0; r < 4; ++r) { mrun[r] = -INFINITY; lrun[r] = 0.f; }

  for (int kt = 0; kt < SEQ_; kt += 64) {
    #pragma unroll
    for (int c = 0; c < 2; ++c) {
      int id = c * 256 + tid;
      {
        int row = id >> 3, ch = id & 7;
        int key = kt + row; if (key > 360) key = 360;
        f16x8 kv = *(const f16x8*)(qkv + (size_t)(b * SEQ_ + key) * RS + C_ + h * 64 + ch * 8);
        *(f16x8*)(Kl + row * 64 + ((ch ^ (row & 7)) << 3)) = kv;
      }
      {
        int kk = id & 63, d0 = (id >> 6) * 8;
        int key = kt + kk; if (key > 360) key = 360;
        f16x8 vv = *(const f16x8*)(qkv + (size_t)(b * SEQ_ + key) * RS + 2 * C_ + h * 64 + d0);
        #pragma unroll
        for (int j = 0; j < 8; ++j) Vt[(d0 + j) * 72 + kk] = vv[j];
      }
    }
    __syncthreads();

    f32x4 s[4] = {};
    #pragma unroll
    for (int f = 0; f < 4; ++f) {
      int row = f * 16 + lo;
      f16x8 k0 = *(const f16x8*)(Kl + row * 64 + ((hi ^ (row & 7)) << 3));
      f16x8 k1 = *(const f16x8*)(Kl + row * 64 + (((hi + 4) ^ (row & 7)) << 3));
      s[f] = __builtin_amdgcn_mfma_f32_16x16x32_f16(qf[0], k0, s[f], 0, 0, 0);
      s[f] = __builtin_amdgcn_mfma_f32_16x16x32_f16(qf[1], k1, s[f], 0, 0, 0);
    }
    float tmax[4] = {-INFINITY, -INFINITY, -INFINITY, -INFINITY};
    #pragma unroll
    for (int f = 0; f < 4; ++f) {
      bool ok = (kt + f * 16 + lo) < SEQ_;
      #pragma unroll
      for (int r = 0; r < 4; ++r) {
        float v = ok ? s[f][r] * 0.125f : -INFINITY;
        s[f][r] = v;
        tmax[r] = fmaxf(tmax[r], v);
      }
    }
    #pragma unroll
    for (int r = 0; r < 4; ++r) {
      #pragma unroll
      for (int mk = 1; mk < 16; mk <<= 1) tmax[r] = fmaxf(tmax[r], __shfl_xor(tmax[r], mk));
    }
    float rsc[4], psum[4] = {0.f, 0.f, 0.f, 0.f};
    #pragma unroll
    for (int r = 0; r < 4; ++r) {
      float mn = fmaxf(mrun[r], tmax[r]);
      rsc[r] = expf(mrun[r] - mn);
      mrun[r] = mn;
    }
    #pragma unroll
    for (int f = 0; f < 4; ++f)
      #pragma unroll
      for (int r = 0; r < 4; ++r) {
        float p = expf(s[f][r] - mrun[r]);
        s[f][r] = p;
        psum[r] += p;
      }
    #pragma unroll
    for (int r = 0; r < 4; ++r) {
      #pragma unroll
      for (int mk = 1; mk < 16; mk <<= 1) psum[r] += __shfl_xor(psum[r], mk);
      lrun[r] = lrun[r] * rsc[r] + psum[r];
    }
    #pragma unroll
    for (int n = 0; n < 4; ++n)
      #pragma unroll
      for (int r = 0; r < 4; ++r) o[n][r] *= rsc[r];
    f16* P = &Pl[w][0];
    #pragma unroll
    for (int f = 0; f < 4; ++f)
      #pragma unroll
      for (int r = 0; r < 4; ++r)
        P[(hi * 4 + r) * 72 + f * 16 + lo] = (f16)s[f][r];
    #pragma unroll
    for (int ks = 0; ks < 2; ++ks) {
      f16x8 pa = *(const f16x8*)(P + lo * 72 + hi * 8 + ks * 32);
      #pragma unroll
      for (int n = 0; n < 4; ++n) {
        f16x8 vf = *(const f16x8*)(Vt + (n * 16 + lo) * 72 + hi * 8 + ks * 32);
        o[n] = __builtin_amdgcn_mfma_f32_16x16x32_f16(pa, vf, o[n], 0, 0, 0);
      }
    }
    __syncthreads();
  }

  #pragma unroll
  for (int r = 0; r < 4; ++r) {
    int row = q0 + hi * 4 + r;
    if (row < SEQ_) {
      float inv = 1.f / lrun[r];
      #pragma unroll
      for (int n = 0; n < 4; ++n)
        Out[(size_t)(b * SEQ_ + row) * C_ + h * 64 + n * 16 + lo] = (f16)(o[n][r] * inv);
    }
  }
}

extern "C" void kernel_launch(void* const* d_in, const int* in_sizes, int n_in,
                              void* d_out, int out_size, void* d_ws, size_t ws_size,
                              hipStream_t stream) {
  (void)in_sizes; (void)n_in; (void)out_size;
  const float* inS   = (const float*)d_in[0];
  const float* inG   = (const float*)d_in[1];
  const float* convW = (const float*)d_in[2];
  const float* Wg    = (const float*)d_in[3];
  const float* qg    = (const float*)d_in[4];
  const float* Wqkv  = (const float*)d_in[5];
  const float* Wproj = (const float*)d_in[6];
  const float* mg    = (const float*)d_in[7];
  const float* Wfc1  = (const float*)d_in[8];
  const float* Wfc2  = (const float*)d_in[9];
  const float* fg    = (const float*)d_in[10];
  float* out = (float*)d_out;

  char* p = (char*)d_ws;
  float* x    = (float*)p;            p += (size_t)MPAD_ * C_ * 4;
  float* bias = (float*)p;            p += (size_t)B_ * C_ * 4;
  float* cost = (float*)p;            p += (size_t)SEQ_ * 64 * 4;
  float* sint = (float*)p;            p += (size_t)SEQ_ * 64 * 4;
  f16*   h16  = (f16*)p;              p += (size_t)MPAD_ * C_ * 2;
  f16*   qkv16= (f16*)p;              p += (size_t)MPAD_ * 3 * C_ * 2;   // reused as g16
  f16*   g16  = qkv16;

  // weight staging: upfront (all layers) if ws allows, else per-layer
  const size_t sq = (size_t)3 * C_ * C_;     // elements per layer, qkv
  const size_t sp = (size_t)C_ * C_;         // proj
  const size_t s1 = (size_t)2 * FFN_ * C_;   // fc1
  const size_t s2 = (size_t)C_ * FFN_;       // fc2
  const size_t per_layer = sq + sp + s1 + s2;
  size_t used_common = (size_t)(p - (char*)d_ws);
  bool upfront = ws_size >= used_common + per_layer * L_ * 2 + 1024;
  size_t mult = upfront ? (size_t)L_ : 1;
  f16* wq  = (f16*)p;
  f16* wpj = wq  + sq * mult;
  f16* w1  = wpj + sp * mult;
  f16* w2  = w1  + s1 * mult;

  bias_kernel<<<dim3((B_ * C_ + 255) / 256), 256, 0, stream>>>(inG, Wg, bias);
  rope_table_kernel<<<dim3((SEQ_ * 32 + 255) / 256), 256, 0, stream>>>(cost, sint);
  conv_kernel<<<dim3(B_, 32), 256, 0, stream>>>(inS, convW, bias, x);

  if (upfront) {
    wcvt_kernel<<<dim3(3 * C_ / 32, C_ / 32, L_), 256, 0, stream>>>(Wqkv, wq, C_, 3 * C_);
    wcvt_kernel<<<dim3(C_ / 32, C_ / 32, L_), 256, 0, stream>>>(Wproj, wpj, C_, C_);
    wcvt_kernel<<<dim3(2 * FFN_ / 32, C_ / 32, L_), 256, 0, stream>>>(Wfc1, w1, C_, 2 * FFN_);
    wcvt_kernel<<<dim3(C_ / 32, FFN_ / 32, L_), 256, 0, stream>>>(Wfc2, w2, FFN_, C_);
  }

  for (int i = 0; i < L_; ++i) {
    if (!upfront) {
      wcvt_kernel<<<dim3(3 * C_ / 32, C_ / 32, 1), 256, 0, stream>>>(Wqkv + (size_t)i * sq, wq, C_, 3 * C_);
      wcvt_kernel<<<dim3(C_ / 32, C_ / 32, 1), 256, 0, stream>>>(Wproj + (size_t)i * sp, wpj, C_, C_);
      wcvt_kernel<<<dim3(2 * FFN_ / 32, C_ / 32, 1), 256, 0, stream>>>(Wfc1 + (size_t)i * s1, w1, C_, 2 * FFN_);
      wcvt_kernel<<<dim3(C_ / 32, FFN_ / 32, 1), 256, 0, stream>>>(Wfc2 + (size_t)i * s2, w2, FFN_, C_);
    }
    const f16* Wq_i = wq  + (upfront ? (size_t)i * sq : 0);
    const f16* Wp_i = wpj + (upfront ? (size_t)i * sp : 0);
    const f16* W1_i = w1  + (upfront ? (size_t)i * s1 : 0);
    const f16* W2_i = w2  + (upfront ? (size_t)i * s2 : 0);

    rmsnorm_kernel<true><<<MPAD_, 256, 0, stream>>>(x, qg + (size_t)i * C_, h16);
    hgemm<0><<<dim3(3 * C_ / 128, MBLK_), 256, 0, stream>>>(h16, Wq_i, qkv16, 3 * C_, C_);
    rope_apply_kernel<<<dim3((M_ * 2 * H_ * 32 + 255) / 256), 256, 0, stream>>>(qkv16, cost, sint);
    attn_kernel<<<dim3(6, H_, B_), 256, 0, stream>>>(qkv16, h16);
    hgemm<1><<<dim3(C_ / 128, MBLK_), 256, 0, stream>>>(h16, Wp_i, x, C_, C_);
    rmsnorm_kernel<true><<<MPAD_, 256, 0, stream>>>(x, mg + (size_t)i * C_, h16);
    hgemm_gate<<<dim3(FFN_ / 64, MBLK_), 256, 0, stream>>>(h16, W1_i, g16);
    hgemm<1><<<dim3(C_ / 128, MBLK_), 256, 0, stream>>>(g16, W2_i, x, C_, FFN_);
  }
  rmsnorm_kernel<false><<<M_, 256, 0, stream>>>(x, fg, out);
}

// Round 6
// 3171.801 us; speedup vs baseline: 8.2563x; 1.1558x over previous
//
#include <hip/hip_runtime.h>
#include <hip/hip_bf16.h>
#include <math.h>

#define B_    32
#define SEQ_  361
#define C_    768
#define H_    12
#define HD_   64
#define FFN_  2048
#define L_    8
#define M_    (B_*SEQ_)          // 11552
#define MPAD_ 11648              // 91 * 128
#define MBLK_ (MPAD_/128)        // 91
#define KC_   224                // conv im2col K (198 padded)

typedef _Float16 f16;
typedef f16  f16x8 __attribute__((ext_vector_type(8)));
typedef float f32x4 __attribute__((ext_vector_type(4)));

#define GLDS(g, l) \
  __builtin_amdgcn_global_load_lds( \
      (const __attribute__((address_space(1))) void*)(g), \
      (__attribute__((address_space(3))) void*)(l), 16, 0, 0)

// ---------------- x_g = input_global @ Wg  (bias per (b, c)) ----------------
__global__ void bias_kernel(const float* __restrict__ inG, const float* __restrict__ Wg,
                            float* __restrict__ bias) {
  int idx = blockIdx.x * blockDim.x + threadIdx.x;
  if (idx >= B_ * C_) return;
  int b = idx / C_, c = idx - b * C_;
  float acc = 0.f;
  #pragma unroll
  for (int j = 0; j < 19; ++j) acc += inG[b * 19 + j] * Wg[j * C_ + c];
  bias[idx] = acc;
}

// ---------------- RoPE cos/sin tables: (SEQ, 64) each ----------------
__global__ void rope_table_kernel(float* __restrict__ cost, float* __restrict__ sint) {
  int idx = blockIdx.x * blockDim.x + threadIdx.x;
  if (idx >= SEQ_ * 32) return;
  int s = idx / 32, j = idx - s * 32;
  float row = (float)(s / 19), col = (float)(s % 19);
  int q = (j < 16) ? j : (j - 16);
  float invf = powf(10000.f, -(float)q / 16.f);
  float ang = ((j < 16) ? row : col) * invf;
  float cv = cosf(ang), sv = sinf(ang);
  cost[s * 64 + j] = cv; cost[s * 64 + j + 32] = cv;
  sint[s * 64 + j] = sv; sint[s * 64 + j + 32] = sv;
}

// ---------------- im2col for conv: A16[MPAD][224] f16 (zero-padded) ----------------
__global__ void im2col_kernel(const float* __restrict__ inS, f16* __restrict__ A16) {
  int idx = blockIdx.x * 256 + threadIdx.x;
  if (idx >= MPAD_ * KC_) return;
  int m = idx / KC_, k = idx - m * KC_;
  float v = 0.f;
  if (m < M_ && k < 198) {
    int b = m / 361, s = m - b * 361;
    int r = s / 19, c = s - r * 19;
    int ci = k / 9, rem = k - ci * 9;
    int dr = rem / 3 - 1, dc = rem - (rem / 3) * 3 - 1;
    int rr = r + dr, cc = c + dc;
    if (rr >= 0 && rr < 19 && cc >= 0 && cc < 19)
      v = inS[(size_t)(b * 22 + ci) * 361 + rr * 19 + cc];
  }
  A16[idx] = (f16)v;
}

// ---------------- conv weight: W[768][198] f32 -> WT[768][224] f16 (pad 0) ----------------
__global__ void wcvt_conv_kernel(const float* __restrict__ W, f16* __restrict__ WT) {
  int idx = blockIdx.x * 256 + threadIdx.x;
  if (idx >= 768 * KC_) return;
  int n = idx / KC_, k = idx - n * KC_;
  WT[idx] = (f16)(k < 198 ? W[n * 198 + k] : 0.f);
}

// ---------------- weight convert + transpose: W[K][N] f32 -> WT[N][K] f16 ----------------
__global__ __launch_bounds__(256) void wcvt_kernel(const float* __restrict__ W,
    f16* __restrict__ WT, int K, int N) {
  __shared__ float t[32][33];
  int n0 = blockIdx.x * 32, k0 = blockIdx.y * 32;
  size_t base = (size_t)blockIdx.z * K * N;
  int c = threadIdx.x & 31, r = threadIdx.x >> 5;
  #pragma unroll
  for (int rr = 0; rr < 32; rr += 8)
    t[r + rr][c] = W[base + (size_t)(k0 + r + rr) * N + n0 + c];
  __syncthreads();
  #pragma unroll
  for (int rr = 0; rr < 32; rr += 8)
    WT[base + (size_t)(n0 + r + rr) * K + k0 + c] = (f16)t[c][r + rr];
}

// ---------------- RMSNorm (C=768), one block per row; f16 or f32 out ----------------
template<bool F16OUT>
__global__ __launch_bounds__(256) void rmsnorm_kernel(const float* __restrict__ X,
    const float* __restrict__ gamma, void* __restrict__ Out) {
  int row = blockIdx.x;
  const float* xp = X + (size_t)row * C_;
  int t = threadIdx.x;
  float v0 = xp[t], v1 = xp[t + 256], v2 = xp[t + 512];
  float ss = v0 * v0 + v1 * v1 + v2 * v2;
  #pragma unroll
  for (int off = 32; off > 0; off >>= 1) ss += __shfl_down(ss, off);
  __shared__ float ws4[4];
  if ((t & 63) == 0) ws4[t >> 6] = ss;
  __syncthreads();
  float tot = ws4[0] + ws4[1] + ws4[2] + ws4[3];
  float r = 1.0f / sqrtf(tot * (1.f / 768.f) + 1e-6f);
  if (F16OUT) {
    f16* op = (f16*)Out + (size_t)row * C_;
    op[t]       = (f16)(v0 * r * gamma[t]);
    op[t + 256] = (f16)(v1 * r * gamma[t + 256]);
    op[t + 512] = (f16)(v2 * r * gamma[t + 512]);
  } else {
    float* op = (float*)Out + (size_t)row * C_;
    op[t]       = v0 * r * gamma[t];
    op[t + 256] = v1 * r * gamma[t + 256];
    op[t + 512] = v2 * r * gamma[t + 512];
  }
}

// ---------------- f16 MFMA GEMM: C = A(MPADxK,f16) @ BT(NxK,f16)^T ----------------
// MODE 0: f16 store (optionally fused RoPE on q/k sections when Cst != null).
// MODE 1: fp32 +=. MODE 2: fp32 = acc + bias[(r/361)*N + n].
// 128x128 tile, BK=32, 4 waves, double-buffered global_load_lds staging.
// LDS logical (row, ch): linear byte = row*64 + (ch ^ ((row>>1)&3))*16 (pre-swizzled src).
template<int MODE>
__global__ __launch_bounds__(256, 3) void hgemm(const f16* __restrict__ A,
    const f16* __restrict__ BT, void* __restrict__ Cout, const float* __restrict__ Bias,
    const float* __restrict__ Cst, const float* __restrict__ Snt,
    int N, int K) {
  __shared__ f16 As[2 * 128 * 32];
  __shared__ f16 Bs[2 * 128 * 32];
  int tid = threadIdx.x;
  int w = tid >> 6, lane = tid & 63, lo = lane & 15, hi = lane >> 4;
  int bm = blockIdx.y * 128, bn = blockIdx.x * 128;
  int wr = (w >> 1) * 64, wc = (w & 1) * 64;
  f32x4 acc[4][4] = {};
  const f16* Abase = A  + (size_t)bm * K;
  const f16* Bbase = BT + (size_t)bn * K;

  int srow = lane >> 2;                       // row within 16-row group
  auto stage = [&](int buf, int kt) {
    #pragma unroll
    for (int j = 0; j < 2; ++j) {
      int r0 = j * 64 + w * 16;
      int row = r0 + srow;
      int chg = (lane & 3) ^ ((row >> 1) & 3);
      GLDS(Abase + (size_t)row * K + kt + chg * 8, As + buf * 4096 + r0 * 32);
      GLDS(Bbase + (size_t)row * K + kt + chg * 8, Bs + buf * 4096 + r0 * 32);
    }
  };

  stage(0, 0);
  __syncthreads();
  int cur = 0;
  for (int kt = 0; kt < K; kt += 32) {
    if (kt + 32 < K) stage(cur ^ 1, kt + 32);
    f16x8 af[4], bf[4];
    #pragma unroll
    for (int m = 0; m < 4; ++m) {
      int row = wr + m * 16 + lo;
      af[m] = *(const f16x8*)(As + cur * 4096 + row * 32 + ((hi ^ ((row >> 1) & 3)) << 3));
    }
    #pragma unroll
    for (int n = 0; n < 4; ++n) {
      int row = wc + n * 16 + lo;
      bf[n] = *(const f16x8*)(Bs + cur * 4096 + row * 32 + ((hi ^ ((row >> 1) & 3)) << 3));
    }
    #pragma unroll
    for (int m = 0; m < 4; ++m)
      #pragma unroll
      for (int n = 0; n < 4; ++n)
        acc[m][n] = __builtin_amdgcn_mfma_f32_16x16x32_f16(af[m], bf[n], acc[m][n], 0, 0, 0);
    __syncthreads();
    cur ^= 1;
  }

  // epilogue; do_rope is wave-uniform (q/k sections end at col 1536, 128-aligned)
  const bool do_rope = (MODE == 0) && (Cst != nullptr) && ((bn + wc) < 1536);
  #pragma unroll
  for (int m = 0; m < 4; ++m) {
    #pragma unroll
    for (int r = 0; r < 4; ++r) {
      int row = bm + wr + m * 16 + hi * 4 + r;
      if (do_rope) {
        int s = row % 361;
        f16* O = (f16*)Cout + (size_t)row * N + bn + wc;
        #pragma unroll
        for (int n = 0; n < 2; ++n) {
          int d = n * 16 + lo;
          float cv = Cst[s * 64 + d], sv = Snt[s * 64 + d];
          float a = acc[m][n][r], b2 = acc[m][n + 2][r];
          O[d]      = (f16)(a * cv - b2 * sv);
          O[d + 32] = (f16)(b2 * cv + a * sv);
        }
      } else {
        #pragma unroll
        for (int n = 0; n < 4; ++n) {
          int col = bn + wc + n * 16 + lo;
          size_t off = (size_t)row * N + col;
          if (MODE == 0) {
            ((f16*)Cout)[off] = (f16)acc[m][n][r];
          } else if (MODE == 1) {
            float* O = (float*)Cout;
            O[off] = O[off] + acc[m][n][r];
          } else {
            int b = row / 361; if (b > 31) b = 31;
            ((float*)Cout)[off] = acc[m][n][r] + Bias[b * N + col];
          }
        }
      }
    }
  }
}

// ---------------- fused fc1 dual-tile + silu gate: G = silu(h@W0) * (h@W1), f16 out ----------------
__global__ __launch_bounds__(256, 3) void hgemm_gate(const f16* __restrict__ A,
    const f16* __restrict__ BT, f16* __restrict__ G) {
  const int K = C_;
  __shared__ f16 As[2 * 128 * 32];
  __shared__ f16 Bs0[2 * 64 * 32];
  __shared__ f16 Bs1[2 * 64 * 32];
  int tid = threadIdx.x;
  int w = tid >> 6, lane = tid & 63, lo = lane & 15, hi = lane >> 4;
  int bm = blockIdx.y * 128, bn = blockIdx.x * 64;
  int wr = (w >> 1) * 64, wc = (w & 1) * 32;
  f32x4 accA[4][2] = {}, accB[4][2] = {};
  const f16* Abase  = A + (size_t)bm * K;
  const f16* B0base = BT + (size_t)bn * K;
  const f16* B1base = BT + (size_t)(2048 + bn) * K;

  int srow = lane >> 2;
  auto stage = [&](int buf, int kt) {
    #pragma unroll
    for (int j = 0; j < 2; ++j) {
      int r0 = j * 64 + w * 16;
      int row = r0 + srow;
      int chg = (lane & 3) ^ ((row >> 1) & 3);
      GLDS(Abase + (size_t)row * K + kt + chg * 8, As + buf * 4096 + r0 * 32);
    }
    int r0 = w * 16;
    int row = r0 + srow;
    int chg = (lane & 3) ^ ((row >> 1) & 3);
    GLDS(B0base + (size_t)row * K + kt + chg * 8, Bs0 + buf * 2048 + r0 * 32);
    GLDS(B1base + (size_t)row * K + kt + chg * 8, Bs1 + buf * 2048 + r0 * 32);
  };

  stage(0, 0);
  __syncthreads();
  int cur = 0;
  for (int kt = 0; kt < K; kt += 32) {
    if (kt + 32 < K) stage(cur ^ 1, kt + 32);
    f16x8 af[4], b0f[2], b1f[2];
    #pragma unroll
    for (int m = 0; m < 4; ++m) {
      int row = wr + m * 16 + lo;
      af[m] = *(const f16x8*)(As + cur * 4096 + row * 32 + ((hi ^ ((row >> 1) & 3)) << 3));
    }
    #pragma unroll
    for (int n = 0; n < 2; ++n) {
      int row = wc + n * 16 + lo;
      int off = cur * 2048 + row * 32 + ((hi ^ ((row >> 1) & 3)) << 3);
      b0f[n] = *(const f16x8*)(Bs0 + off);
      b1f[n] = *(const f16x8*)(Bs1 + off);
    }
    #pragma unroll
    for (int m = 0; m < 4; ++m)
      #pragma unroll
      for (int n = 0; n < 2; ++n) {
        accA[m][n] = __builtin_amdgcn_mfma_f32_16x16x32_f16(af[m], b0f[n], accA[m][n], 0, 0, 0);
        accB[m][n] = __builtin_amdgcn_mfma_f32_16x16x32_f16(af[m], b1f[n], accB[m][n], 0, 0, 0);
      }
    __syncthreads();
    cur ^= 1;
  }

  #pragma unroll
  for (int m = 0; m < 4; ++m)
    #pragma unroll
    for (int n = 0; n < 2; ++n)
      #pragma unroll
      for (int r = 0; r < 4; ++r) {
        float a = accA[m][n][r], bb = accB[m][n][r];
        float g = a / (1.f + expf(-a)) * bb;
        G[(size_t)(bm + wr + m * 16 + hi * 4 + r) * 2048 + bn + wc + n * 16 + lo] = (f16)g;
      }
}

// ---------------- MFMA flash attention: block = (64 q-rows, h, b), 4 waves ----------------
__global__ __launch_bounds__(256, 2) void attn_kernel(const f16* __restrict__ qkv,
                                                      f16* __restrict__ Out) {
  __shared__ f16 Kl[64 * 64];        // swizzled: chunk ^= (row&7)
  __shared__ f16 Vt[64 * 72];        // [d][key], pad 8
  __shared__ f16 Pl[4][16 * 72];     // per-wave P [q][key], pad 8
  int tid = threadIdx.x;
  int w = tid >> 6, lane = tid & 63, lo = lane & 15, hi = lane >> 4;
  int qt = blockIdx.x, h = blockIdx.y, b = blockIdx.z;
  int q0 = qt * 64 + w * 16;
  const int RS = 3 * C_;

  f16x8 qf[2];
  {
    int qrow = q0 + lo; if (qrow > 360) qrow = 360;
    const f16* qp = qkv + (size_t)(b * SEQ_ + qrow) * RS + h * 64 + hi * 8;
    qf[0] = *(const f16x8*)(qp);
    qf[1] = *(const f16x8*)(qp + 32);
  }
  f32x4 o[4] = {};
  float mrun[4], lrun[4];
  #pragma unroll
  for (int r = 0; r < 4; ++r) { mrun[r] = -INFINITY; lrun[r] = 0.f; }

  for (int kt = 0; kt < SEQ_; kt += 64) {
    #pragma unroll
    for (int c = 0; c < 2; ++c) {
      int id = c * 256 + tid;
      {
        int row = id >> 3, ch = id & 7;
        int key = kt + row; if (key > 360) key = 360;
        f16x8 kv = *(const f16x8*)(qkv + (size_t)(b * SEQ_ + key) * RS + C_ + h * 64 + ch * 8);
        *(f16x8*)(Kl + row * 64 + ((ch ^ (row & 7)) << 3)) = kv;
      }
      {
        int kk = id & 63, d0 = (id >> 6) * 8;
        int key = kt + kk; if (key > 360) key = 360;
        f16x8 vv = *(const f16x8*)(qkv + (size_t)(b * SEQ_ + key) * RS + 2 * C_ + h * 64 + d0);
        #pragma unroll
        for (int j = 0; j < 8; ++j) Vt[(d0 + j) * 72 + kk] = vv[j];
      }
    }
    __syncthreads();

    f32x4 s[4] = {};
    #pragma unroll
    for (int f = 0; f < 4; ++f) {
      int row = f * 16 + lo;
      f16x8 k0 = *(const f16x8*)(Kl + row * 64 + ((hi ^ (row & 7)) << 3));
      f16x8 k1 = *(const f16x8*)(Kl + row * 64 + (((hi + 4) ^ (row & 7)) << 3));
      s[f] = __builtin_amdgcn_mfma_f32_16x16x32_f16(qf[0], k0, s[f], 0, 0, 0);
      s[f] = __builtin_amdgcn_mfma_f32_16x16x32_f16(qf[1], k1, s[f], 0, 0, 0);
    }
    float tmax[4] = {-INFINITY, -INFINITY, -INFINITY, -INFINITY};
    #pragma unroll
    for (int f = 0; f < 4; ++f) {
      bool ok = (kt + f * 16 + lo) < SEQ_;
      #pragma unroll
      for (int r = 0; r < 4; ++r) {
        float v = ok ? s[f][r] * 0.125f : -INFINITY;
        s[f][r] = v;
        tmax[r] = fmaxf(tmax[r], v);
      }
    }
    #pragma unroll
    for (int r = 0; r < 4; ++r) {
      #pragma unroll
      for (int mk = 1; mk < 16; mk <<= 1) tmax[r] = fmaxf(tmax[r], __shfl_xor(tmax[r], mk));
    }
    float rsc[4], psum[4] = {0.f, 0.f, 0.f, 0.f};
    #pragma unroll
    for (int r = 0; r < 4; ++r) {
      float mn = fmaxf(mrun[r], tmax[r]);
      rsc[r] = expf(mrun[r] - mn);
      mrun[r] = mn;
    }
    #pragma unroll
    for (int f = 0; f < 4; ++f)
      #pragma unroll
      for (int r = 0; r < 4; ++r) {
        float p = expf(s[f][r] - mrun[r]);
        s[f][r] = p;
        psum[r] += p;
      }
    #pragma unroll
    for (int r = 0; r < 4; ++r) {
      #pragma unroll
      for (int mk = 1; mk < 16; mk <<= 1) psum[r] += __shfl_xor(psum[r], mk);
      lrun[r] = lrun[r] * rsc[r] + psum[r];
    }
    #pragma unroll
    for (int n = 0; n < 4; ++n)
      #pragma unroll
      for (int r = 0; r < 4; ++r) o[n][r] *= rsc[r];
    f16* P = &Pl[w][0];
    #pragma unroll
    for (int f = 0; f < 4; ++f)
      #pragma unroll
      for (int r = 0; r < 4; ++r)
        P[(hi * 4 + r) * 72 + f * 16 + lo] = (f16)s[f][r];
    #pragma unroll
    for (int ks = 0; ks < 2; ++ks) {
      f16x8 pa = *(const f16x8*)(P + lo * 72 + hi * 8 + ks * 32);
      #pragma unroll
      for (int n = 0; n < 4; ++n) {
        f16x8 vf = *(const f16x8*)(Vt + (n * 16 + lo) * 72 + hi * 8 + ks * 32);
        o[n] = __builtin_amdgcn_mfma_f32_16x16x32_f16(pa, vf, o[n], 0, 0, 0);
      }
    }
    __syncthreads();
  }

  #pragma unroll
  for (int r = 0; r < 4; ++r) {
    int row = q0 + hi * 4 + r;
    if (row < SEQ_) {
      float inv = 1.f / lrun[r];
      #pragma unroll
      for (int n = 0; n < 4; ++n)
        Out[(size_t)(b * SEQ_ + row) * C_ + h * 64 + n * 16 + lo] = (f16)(o[n][r] * inv);
    }
  }
}

extern "C" void kernel_launch(void* const* d_in, const int* in_sizes, int n_in,
                              void* d_out, int out_size, void* d_ws, size_t ws_size,
                              hipStream_t stream) {
  (void)in_sizes; (void)n_in; (void)out_size;
  const float* inS   = (const float*)d_in[0];
  const float* inG   = (const float*)d_in[1];
  const float* convW = (const float*)d_in[2];
  const float* Wg    = (const float*)d_in[3];
  const float* qg    = (const float*)d_in[4];
  const float* Wqkv  = (const float*)d_in[5];
  const float* Wproj = (const float*)d_in[6];
  const float* mg    = (const float*)d_in[7];
  const float* Wfc1  = (const float*)d_in[8];
  const float* Wfc2  = (const float*)d_in[9];
  const float* fg    = (const float*)d_in[10];
  float* out = (float*)d_out;

  char* p = (char*)d_ws;
  float* x    = (float*)p;            p += (size_t)MPAD_ * C_ * 4;
  float* bias = (float*)p;            p += (size_t)B_ * C_ * 4;
  float* cost = (float*)p;            p += (size_t)SEQ_ * 64 * 4;
  float* sint = (float*)p;            p += (size_t)SEQ_ * 64 * 4;
  f16*   h16  = (f16*)p;              p += (size_t)MPAD_ * C_ * 2;
  f16*   qkv16= (f16*)p;              p += (size_t)MPAD_ * 3 * C_ * 2;   // reused as g16
  f16*   a16c = (f16*)p;              p += (size_t)MPAD_ * KC_ * 2;     // conv im2col
  f16*   wc16 = (f16*)p;              p += (size_t)C_ * KC_ * 2;        // conv weight
  f16*   g16  = qkv16;

  const size_t sq = (size_t)3 * C_ * C_;
  const size_t sp = (size_t)C_ * C_;
  const size_t s1 = (size_t)2 * FFN_ * C_;
  const size_t s2 = (size_t)C_ * FFN_;
  const size_t per_layer = sq + sp + s1 + s2;
  size_t used_common = (size_t)(p - (char*)d_ws);
  bool upfront = ws_size >= used_common + per_layer * L_ * 2 + 1024;
  size_t mult = upfront ? (size_t)L_ : 1;
  f16* wq  = (f16*)p;
  f16* wpj = wq  + sq * mult;
  f16* w1  = wpj + sp * mult;
  f16* w2  = w1  + s1 * mult;

  bias_kernel<<<dim3((B_ * C_ + 255) / 256), 256, 0, stream>>>(inG, Wg, bias);
  rope_table_kernel<<<dim3((SEQ_ * 32 + 255) / 256), 256, 0, stream>>>(cost, sint);
  im2col_kernel<<<dim3((MPAD_ * KC_ + 255) / 256), 256, 0, stream>>>(inS, a16c);
  wcvt_conv_kernel<<<dim3((768 * KC_ + 255) / 256), 256, 0, stream>>>(convW, wc16);
  hgemm<2><<<dim3(C_ / 128, MBLK_), 256, 0, stream>>>(a16c, wc16, x, bias, nullptr, nullptr, C_, KC_);

  if (upfront) {
    wcvt_kernel<<<dim3(3 * C_ / 32, C_ / 32, L_), 256, 0, stream>>>(Wqkv, wq, C_, 3 * C_);
    wcvt_kernel<<<dim3(C_ / 32, C_ / 32, L_), 256, 0, stream>>>(Wproj, wpj, C_, C_);
    wcvt_kernel<<<dim3(2 * FFN_ / 32, C_ / 32, L_), 256, 0, stream>>>(Wfc1, w1, C_, 2 * FFN_);
    wcvt_kernel<<<dim3(C_ / 32, FFN_ / 32, L_), 256, 0, stream>>>(Wfc2, w2, FFN_, C_);
  }

  for (int i = 0; i < L_; ++i) {
    if (!upfront) {
      wcvt_kernel<<<dim3(3 * C_ / 32, C_ / 32, 1), 256, 0, stream>>>(Wqkv + (size_t)i * sq, wq, C_, 3 * C_);
      wcvt_kernel<<<dim3(C_ / 32, C_ / 32, 1), 256, 0, stream>>>(Wproj + (size_t)i * sp, wpj, C_, C_);
      wcvt_kernel<<<dim3(2 * FFN_ / 32, C_ / 32, 1), 256, 0, stream>>>(Wfc1 + (size_t)i * s1, w1, C_, 2 * FFN_);
      wcvt_kernel<<<dim3(C_ / 32, FFN_ / 32, 1), 256, 0, stream>>>(Wfc2 + (size_t)i * s2, w2, FFN_, C_);
    }
    const f16* Wq_i = wq  + (upfront ? (size_t)i * sq : 0);
    const f16* Wp_i = wpj + (upfront ? (size_t)i * sp : 0);
    const f16* W1_i = w1  + (upfront ? (size_t)i * s1 : 0);
    const f16* W2_i = w2  + (upfront ? (size_t)i * s2 : 0);

    rmsnorm_kernel<true><<<MPAD_, 256, 0, stream>>>(x, qg + (size_t)i * C_, h16);
    hgemm<0><<<dim3(3 * C_ / 128, MBLK_), 256, 0, stream>>>(
        h16, Wq_i, qkv16, nullptr, cost, sint, 3 * C_, C_);
    attn_kernel<<<dim3(6, H_, B_), 256, 0, stream>>>(qkv16, h16);
    hgemm<1><<<dim3(C_ / 128, MBLK_), 256, 0, stream>>>(
        h16, Wp_i, x, nullptr, nullptr, nullptr, C_, C_);
    rmsnorm_kernel<true><<<MPAD_, 256, 0, stream>>>(x, mg + (size_t)i * C_, h16);
    hgemm_gate<<<dim3(FFN_ / 64, MBLK_), 256, 0, stream>>>(h16, W1_i, g16);
    hgemm<1><<<dim3(C_ / 128, MBLK_), 256, 0, stream>>>(
        g16, W2_i, x, nullptr, nullptr, nullptr, C_, FFN_);
  }
  rmsnorm_kernel<false><<<M_, 256, 0, stream>>>(x, fg, out);
}